// Round 10
// baseline (175.996 us; speedup 1.0000x reference)
//
#include <hip/hip_runtime.h>
#include <hip/hip_bf16.h>

#define NS 8192
#define NQ 8192
#define NTOT 16384
#define KDIM 1024
#define ED 512
#define NC 64
#define PBLK 64   // proto partial row-chunks along support dim

typedef __attribute__((ext_vector_type(4))) float fx4;
typedef __attribute__((ext_vector_type(8))) short sx8;
typedef __attribute__((ext_vector_type(8))) unsigned short ux8;

__device__ __forceinline__ unsigned short f2bf(float f) {
  union { float f; unsigned u; } v; v.f = f;
  unsigned r = v.u + 0x7fffu + ((v.u >> 16) & 1u);   // RNE
  return (unsigned short)(r >> 16);
}
__device__ __forceinline__ float bf2f(unsigned short h) {
  union { unsigned u; float f; } v; v.u = ((unsigned)h) << 16;
  return v.f;
}

// ---------------------------------------------------------------------------
// K0: W -> Wtp, bf16 in MFMA B-FRAGMENT-PACKED order:
//   flat chunk c = n64*8192 + kt*512 + s2*256 + j*64 + lane   (c in [0,65536))
//   chunk c holds B[n][kb..kb+8) where n = n64*64 + j*16 + (lane&15),
//   kb = kt*64 + (s2*4 + (lane>>4))*8.
// Waves in k_gemm load B-fragments as coalesced 1KB global_load_dwordx4
// (lane-consecutive chunks) -> B never touches LDS. Also zeroes rowssq.
// ---------------------------------------------------------------------------
__global__ __launch_bounds__(256) void k_prep(
    const float* __restrict__ W, unsigned short* __restrict__ Wtp,
    float* __restrict__ rowssq) {
  int c = blockIdx.x * 256 + threadIdx.x;   // 0..65535
  int lane = c & 63;
  int j    = (c >> 6) & 3;
  int s2   = (c >> 8) & 1;
  int kt   = (c >> 9) & 15;
  int n64  = c >> 13;
  int quad = lane >> 4, ml = lane & 15;
  int n  = n64 * 64 + j * 16 + ml;
  int kb = kt * 64 + (s2 * 4 + quad) * 8;
  ux8 o;
#pragma unroll
  for (int e = 0; e < 8; ++e) o[e] = f2bf(W[(size_t)(kb + e) * ED + n]);
  *(ux8*)&Wtp[(size_t)c * 8] = o;
  if (c < NTOT) rowssq[c] = 0.f;
}

// ---------------------------------------------------------------------------
// K1: emb = bf16(X) @ W + per-row ssq, X read as fp32 with fused cvt.
// R7 POST-MORTEM: traffic ideal (37/18.4 MB), no vmcnt, LDS halved — and
// duration didn't move (50us, MfmaUtil 12.6%). MFMA-busy (6.3us) is already
// at its floor; the 44us gap is un-hidden latency at 2 waves/SIMD lockstep.
// R8 FIX: raise TLP. Tile 64x128 (was 128x128), 4 waves of 64r x 32c,
// grid 1024 -> 4 blocks/CU = 16 waves/CU = 4 waves/SIMD (2x R7).
//   - 64 rows/wave KEPT so B L2 re-read traffic stays 256 MB (B slice read
//     once per 64-row wave; halving rows/wave would double it).
//   - regs shrink: acc 32, avX 2x8, bf 16 -> ~105 VGPR; launch_bounds(256,4)
//     pins 4 waves/SIMD. Spill watch: WRITE_SIZE must stay ~18.4 MB.
//   - pipeline unchanged: named avA/avB depth-2 (rule #20), B-frags direct
//     from fragment-packed Wtp (L2-hot), lgkmcnt(0)+s_barrier only per step.
// ---------------------------------------------------------------------------
__global__ __launch_bounds__(256, 4) void k_gemm_embed(
    const float* __restrict__ Xs, const float* __restrict__ Xq,
    const unsigned short* __restrict__ Wtp,
    unsigned short* __restrict__ emb, float* __restrict__ rowssq) {
  __shared__ unsigned short Ash[2][64 * 8 * 8];  // 8 KB per buf, [m*8+slot][8]

  int lid = blockIdx.x;            // 0..1023
  int x = lid & 7;                 // xcd round-robin heuristic
  int s = lid >> 3;                // 0..127
  int m_blk = x * 32 + (s >> 2);   // 0..255 (64-row tiles)
  int n_blk = s & 3;               // 0..3

  const float* Xsrc = (m_blk < 128)
      ? (Xs + (size_t)m_blk * 64 * KDIM)
      : (Xq + (size_t)(m_blk - 128) * 64 * KDIM);

  int t = threadIdx.x;
  int lane = t & 63, w = t >> 6;   // w = 0..3: 32-col slice index
  int quad = lane >> 4, ml = lane & 15;
  int n64 = n_blk * 2 + (w >> 1);  // 64-col packing unit
  int jb = (w & 1) * 2;            // j base inside the n64 unit

  // per-wave B fragment base: chunk (n64*8192 + lane), element *8
  const unsigned short* Bbase = Wtp + ((size_t)n64 * 8192 + lane) * 8;

  fx4 acc[4][2];                   // [row-frag i<4][col-frag j<2]
#pragma unroll
  for (int i = 0; i < 4; ++i)
#pragma unroll
    for (int j = 0; j < 2; ++j) acc[i][j] = fx4{0.f, 0.f, 0.f, 0.f};

  fx4 avA[2][2], avB[2][2];        // NAMED A double-buffer (rule #20)

  auto loadA = [&](int kt, fx4 (&av)[2][2]) {
    int k0 = kt * 64;
#pragma unroll
    for (int c = 0; c < 2; ++c) {            // A: 512 chunks of 8, 2/thread
      int ch = t + 256 * c;
      int m = ch >> 3, kq = ch & 7;          // kq = GLOBAL k-octet
      const float* g = &Xsrc[(size_t)m * KDIM + k0 + kq * 8];
      av[c][0] = *(const fx4*)g;
      av[c][1] = *(const fx4*)(g + 4);
    }
  };
  auto writeA = [&](const fx4 (&av)[2][2], int bbuf) {
#pragma unroll
    for (int c = 0; c < 2; ++c) {
      int ch = t + 256 * c;
      int m = ch >> 3, kq = ch & 7;
      ux8 o;
      o[0] = f2bf(av[c][0].x); o[1] = f2bf(av[c][0].y);
      o[2] = f2bf(av[c][0].z); o[3] = f2bf(av[c][0].w);
      o[4] = f2bf(av[c][1].x); o[5] = f2bf(av[c][1].y);
      o[6] = f2bf(av[c][1].z); o[7] = f2bf(av[c][1].w);
      *(ux8*)&Ash[bbuf][((m * 8) + (kq ^ (m & 7))) * 8] = o;   // slot swizzle
    }
  };
  auto loadB = [&](int kt, sx8 (&bf)[2][2]) {
#pragma unroll
    for (int s2 = 0; s2 < 2; ++s2)
#pragma unroll
      for (int j = 0; j < 2; ++j)
        bf[s2][j] = *(const sx8*)&Bbase[(size_t)(kt * 512 + s2 * 256 + (jb + j) * 64) * 8];
  };
  auto compute = [&](int b, const sx8 (&bf)[2][2]) {
#pragma unroll
    for (int s2 = 0; s2 < 2; ++s2) {
      int kq = s2 * 4 + quad;
      sx8 af[4];
#pragma unroll
      for (int i = 0; i < 4; ++i) {
        int row = i * 16 + ml;
        af[i] = *(const sx8*)&Ash[b][(row * 8 + (kq ^ (row & 7))) * 8];
      }
#pragma unroll
      for (int i = 0; i < 4; ++i)
#pragma unroll
        for (int j = 0; j < 2; ++j)
          acc[i][j] = __builtin_amdgcn_mfma_f32_16x16x32_bf16(af[i], bf[s2][j], acc[i][j], 0, 0, 0);
    }
  };
  auto sync_step = [&]() {
    // only LDS ordering needed: A ds_writes commit; reg-loads stay in flight
    __builtin_amdgcn_sched_barrier(0);
    asm volatile("s_waitcnt lgkmcnt(0)" ::: "memory");
    __builtin_amdgcn_s_barrier();
    __builtin_amdgcn_sched_barrier(0);
  };

  // ---- prologue: A(0)->avA->Ash[0]; A(1)->avB stays in flight
  loadA(0, avA);
  loadA(1, avB);
  writeA(avA, 0);        // auto vmcnt wait on avA only
  sync_step();

  for (int it = 0; it < 8; ++it) {
    int kt0 = it * 2;
    sx8 bf[2][2];
    // ---- even step kt0, compute from Ash[0]; avB holds A(kt0+1) in flight
    loadB(kt0, bf);
    loadA(kt0 + 2 < 16 ? kt0 + 2 : 15, avA);
    compute(0, bf);
    writeA(avB, 1);      // cvt A(kt0+1) (auto-wait, ~1 step of cover) -> Ash[1]
    sync_step();

    // ---- odd step kt0+1, compute from Ash[1]; avA holds A(kt0+2) in flight
    loadB(kt0 + 1, bf);
    loadA(kt0 + 3 < 16 ? kt0 + 3 : 15, avB);
    compute(1, bf);
    writeA(avA, 0);      // cvt A(kt0+2) -> Ash[0]
    sync_step();
  }

  // epilogue: emb store + row-ssq partial (shfl width-16 + 1 atomic per row)
  int grow = m_blk * 64;
  int gcol = n_blk * 128 + w * 32;
#pragma unroll
  for (int i = 0; i < 4; ++i) {
#pragma unroll
    for (int r = 0; r < 4; ++r) {
      int mrow = grow + i * 16 + quad * 4 + r;
      float p = 0.f;
#pragma unroll
      for (int j = 0; j < 2; ++j) {
        emb[(size_t)mrow * ED + gcol + j * 16 + ml] = f2bf(acc[i][j][r]);
        p += acc[i][j][r] * acc[i][j][r];
      }
#pragma unroll
      for (int off = 1; off < 16; off <<= 1) p += __shfl_xor(p, off, 16);
      if (ml == 0) atomicAdd(&rowssq[mrow], p);
    }
  }
}

// ---------------------------------------------------------------------------
// K2: per-class partial sums of (emb_s / ||s||), LDS-accumulated.
// ---------------------------------------------------------------------------
__global__ __launch_bounds__(256) void k_proto_partial(
    const unsigned short* __restrict__ embS, const float* __restrict__ rowssq,
    const int* __restrict__ labels, float* __restrict__ Ppart) {
  __shared__ float Pl[NC * 64];  // 16 KB: [class][dim-within-slice]
  int t = threadIdx.x;
#pragma unroll
  for (int i = 0; i < 16; ++i) Pl[i * 256 + t] = 0.f;
  __syncthreads();

  int w = t >> 6, lane = t & 63;
  int ds = blockIdx.y;            // dim slice: dims [ds*64, ds*64+64)
  int row0 = blockIdx.x * (NS / PBLK);
#pragma unroll 4
  for (int r = w; r < NS / PBLK; r += 4) {
    int row = row0 + r;
    int lbl = labels[row];
    float scale = 1.0f / fmaxf(sqrtf(rowssq[row]), 1e-12f);
    float v = bf2f(embS[(size_t)row * ED + ds * 64 + lane]) * scale;
    atomicAdd(&Pl[lbl * 64 + lane], v);
  }
  __syncthreads();

  float* o = Ppart + (size_t)blockIdx.x * NC * ED + ds * 64;
#pragma unroll
  for (int i = 0; i < 16; ++i) {
    int idx = i * 256 + t;
    o[(size_t)(idx >> 6) * ED + (idx & 63)] = Pl[idx];
  }
}

// ---------------------------------------------------------------------------
// K3: reduce PBLK partials -> Pbf (bf16, MFMA B-fragment layout [kq][n][8]).
// ---------------------------------------------------------------------------
__global__ __launch_bounds__(256) void k_proto_reduce(
    const float* __restrict__ Ppart, unsigned short* __restrict__ Pbf) {
  int idx = blockIdx.x * 256 + threadIdx.x;  // 0..NC*ED-1
  int kq = idx >> 9;
  int n = (idx >> 3) & 63;
  int j = idx & 7;
  int d = kq * 8 + j;
  float s = 0.f;
#pragma unroll 8
  for (int b = 0; b < PBLK; ++b) s += Ppart[(size_t)b * NC * ED + n * ED + d];
  Pbf[idx] = f2bf(s);
}

// ---------------------------------------------------------------------------
// K4: class_scores = (emb_q @ P^T) / ||q|| + fused softmax.
// ---------------------------------------------------------------------------
__global__ __launch_bounds__(64) void k_scores(
    const unsigned short* __restrict__ embQ, const float* __restrict__ ssqQ,
    const unsigned short* __restrict__ Pbf, float* __restrict__ out) {
  int lane = threadIdx.x;
  int quad = lane >> 4, ml = lane & 15;
  int qrow0 = blockIdx.x * 16;

  fx4 acc[4];
#pragma unroll
  for (int i = 0; i < 4; ++i) acc[i] = fx4{0.f, 0.f, 0.f, 0.f};

#pragma unroll 4
  for (int ki = 0; ki < 16; ++ki) {
    sx8 a = *(const sx8*)&embQ[(size_t)(qrow0 + ml) * ED + ki * 32 + quad * 8];
#pragma unroll
    for (int nt = 0; nt < 4; ++nt) {
      sx8 b = *(const sx8*)&Pbf[((ki * 4 + quad) * 64 + nt * 16 + ml) * 8];
      acc[nt] = __builtin_amdgcn_mfma_f32_16x16x32_bf16(a, b, acc[nt], 0, 0, 0);
    }
  }

#pragma unroll
  for (int r = 0; r < 4; ++r) {
    int qq = qrow0 + quad * 4 + r;
    float scale = 1.0f / fmaxf(sqrtf(ssqQ[qq]), 1e-12f);
    float s[4];
#pragma unroll
    for (int nt = 0; nt < 4; ++nt) s[nt] = acc[nt][r] * scale;
    float m = fmaxf(fmaxf(s[0], s[1]), fmaxf(s[2], s[3]));
#pragma unroll
    for (int off = 1; off < 16; off <<= 1) m = fmaxf(m, __shfl_xor(m, off, 16));
    float e[4], ssum = 0.f;
#pragma unroll
    for (int nt = 0; nt < 4; ++nt) { e[nt] = __expf(s[nt] - m); ssum += e[nt]; }
#pragma unroll
    for (int off = 1; off < 16; off <<= 1) ssum += __shfl_xor(ssum, off, 16);
    float inv = 1.0f / ssum;
#pragma unroll
    for (int nt = 0; nt < 4; ++nt)
      out[(size_t)qq * NC + nt * 16 + ml] = e[nt] * inv;
  }
}

// ---------------------------------------------------------------------------
extern "C" void kernel_launch(void* const* d_in, const int* in_sizes, int n_in,
                              void* d_out, int out_size, void* d_ws, size_t ws_size,
                              hipStream_t stream) {
  const float* Xs     = (const float*)d_in[0];  // support_data [8192,1024]
  const int*   labels = (const int*)d_in[1];    // support_labels [8192]
  const float* Xq     = (const float*)d_in[2];  // query_data [8192,1024]
  const float* W      = (const float*)d_in[3];  // W [1024,512]
  float* out = (float*)d_out;

  char* ws = (char*)d_ws;
  size_t off = 0;
  unsigned short* Wtp = (unsigned short*)(ws + off); off += (size_t)ED * KDIM * 2;    // 1 MB (fragment-packed)
  unsigned short* emb = (unsigned short*)(ws + off); off += (size_t)NTOT * ED * 2;    // 16 MB
  float* rowssq = (float*)(ws + off); off += (size_t)NTOT * 4;                        // 64 KB
  float* Ppart  = (float*)(ws + off); off += (size_t)PBLK * NC * ED * 4;              // 8 MB
  unsigned short* Pbf = (unsigned short*)(ws + off); off += (size_t)NC * ED * 2;      // 64 KB

  k_prep<<<256, 256, 0, stream>>>(W, Wtp, rowssq);
  k_gemm_embed<<<1024, 256, 0, stream>>>(Xs, Xq, Wtp, emb, rowssq);
  k_proto_partial<<<dim3(PBLK, 8), 256, 0, stream>>>(emb, rowssq, labels, Ppart);
  k_proto_reduce<<<NC * ED / 256, 256, 0, stream>>>(Ppart, Pbf);
  k_scores<<<NQ / 16, 64, 0, stream>>>(emb + (size_t)NS * ED, rowssq + NS, Pbf, out);
}

// Round 12
// 173.435 us; speedup vs baseline: 1.0148x; 1.0148x over previous
//
#include <hip/hip_runtime.h>
#include <hip/hip_bf16.h>

#define NS 8192
#define NQ 8192
#define NTOT 16384
#define KDIM 1024
#define ED 512
#define NC 64

typedef __attribute__((ext_vector_type(4))) float fx4;
typedef __attribute__((ext_vector_type(8))) short sx8;
typedef __attribute__((ext_vector_type(8))) unsigned short ux8;

__device__ __forceinline__ unsigned short f2bf(float f) {
  union { float f; unsigned u; } v; v.f = f;
  unsigned r = v.u + 0x7fffu + ((v.u >> 16) & 1u);   // RNE
  return (unsigned short)(r >> 16);
}
__device__ __forceinline__ float bf2f(unsigned short h) {
  union { unsigned u; float f; } v; v.u = ((unsigned)h) << 16;
  return v.f;
}

// ---------------------------------------------------------------------------
// K0: W -> Wtp, bf16 in MFMA B-FRAGMENT-PACKED order:
//   flat chunk c = n64*8192 + kt*512 + s2*256 + j*64 + lane   (c in [0,65536))
//   chunk c holds B[n][kb..kb+8) where n = n64*64 + j*16 + (lane&15),
//   kb = kt*64 + (s2*4 + (lane>>4))*8.
// Also zeroes rowssq (16K floats) and Pacc (32K floats, proto accumulator).
// ---------------------------------------------------------------------------
__global__ __launch_bounds__(256) void k_prep(
    const float* __restrict__ W, unsigned short* __restrict__ Wtp,
    float* __restrict__ rowssq, float* __restrict__ Pacc) {
  int c = blockIdx.x * 256 + threadIdx.x;   // 0..65535
  int lane = c & 63;
  int j    = (c >> 6) & 3;
  int s2   = (c >> 8) & 1;
  int kt   = (c >> 9) & 15;
  int n64  = c >> 13;
  int quad = lane >> 4, ml = lane & 15;
  int n  = n64 * 64 + j * 16 + ml;
  int kb = kt * 64 + (s2 * 4 + quad) * 8;
  ux8 o;
#pragma unroll
  for (int e = 0; e < 8; ++e) o[e] = f2bf(W[(size_t)(kb + e) * ED + n]);
  *(ux8*)&Wtp[(size_t)c * 8] = o;
  if (c < NTOT) rowssq[c] = 0.f;
  if (c < NC * ED) Pacc[c] = 0.f;
}

// ---------------------------------------------------------------------------
// K1: emb = bf16(X) @ W + per-row ssq. UNCHANGED from R8 (plateaued ~51us:
// three structural changes — 128^2 tile, B-bypass, 2x TLP — all left duration
// invariant with MFMA-busy at its floor; per R9's decision rule this kernel
// is frozen and the session attacks the ~120us of non-gemm time instead).
// ---------------------------------------------------------------------------
__global__ __launch_bounds__(256, 4) void k_gemm_embed(
    const float* __restrict__ Xs, const float* __restrict__ Xq,
    const unsigned short* __restrict__ Wtp,
    unsigned short* __restrict__ emb, float* __restrict__ rowssq) {
  __shared__ unsigned short Ash[2][64 * 8 * 8];  // 8 KB per buf, [m*8+slot][8]

  int lid = blockIdx.x;            // 0..1023
  int x = lid & 7;                 // xcd round-robin heuristic
  int s = lid >> 3;                // 0..127
  int m_blk = x * 32 + (s >> 2);   // 0..255 (64-row tiles)
  int n_blk = s & 3;               // 0..3

  const float* Xsrc = (m_blk < 128)
      ? (Xs + (size_t)m_blk * 64 * KDIM)
      : (Xq + (size_t)(m_blk - 128) * 64 * KDIM);

  int t = threadIdx.x;
  int lane = t & 63, w = t >> 6;   // w = 0..3: 32-col slice index
  int quad = lane >> 4, ml = lane & 15;
  int n64 = n_blk * 2 + (w >> 1);  // 64-col packing unit
  int jb = (w & 1) * 2;            // j base inside the n64 unit

  const unsigned short* Bbase = Wtp + ((size_t)n64 * 8192 + lane) * 8;

  fx4 acc[4][2];
#pragma unroll
  for (int i = 0; i < 4; ++i)
#pragma unroll
    for (int j = 0; j < 2; ++j) acc[i][j] = fx4{0.f, 0.f, 0.f, 0.f};

  fx4 avA[2][2], avB[2][2];        // NAMED A double-buffer (rule #20)

  auto loadA = [&](int kt, fx4 (&av)[2][2]) {
    int k0 = kt * 64;
#pragma unroll
    for (int c = 0; c < 2; ++c) {
      int ch = t + 256 * c;
      int m = ch >> 3, kq = ch & 7;
      const float* g = &Xsrc[(size_t)m * KDIM + k0 + kq * 8];
      av[c][0] = *(const fx4*)g;
      av[c][1] = *(const fx4*)(g + 4);
    }
  };
  auto writeA = [&](const fx4 (&av)[2][2], int bbuf) {
#pragma unroll
    for (int c = 0; c < 2; ++c) {
      int ch = t + 256 * c;
      int m = ch >> 3, kq = ch & 7;
      ux8 o;
      o[0] = f2bf(av[c][0].x); o[1] = f2bf(av[c][0].y);
      o[2] = f2bf(av[c][0].z); o[3] = f2bf(av[c][0].w);
      o[4] = f2bf(av[c][1].x); o[5] = f2bf(av[c][1].y);
      o[6] = f2bf(av[c][1].z); o[7] = f2bf(av[c][1].w);
      *(ux8*)&Ash[bbuf][((m * 8) + (kq ^ (m & 7))) * 8] = o;
    }
  };
  auto loadB = [&](int kt, sx8 (&bf)[2][2]) {
#pragma unroll
    for (int s2 = 0; s2 < 2; ++s2)
#pragma unroll
      for (int j = 0; j < 2; ++j)
        bf[s2][j] = *(const sx8*)&Bbase[(size_t)(kt * 512 + s2 * 256 + (jb + j) * 64) * 8];
  };
  auto compute = [&](int b, const sx8 (&bf)[2][2]) {
#pragma unroll
    for (int s2 = 0; s2 < 2; ++s2) {
      int kq = s2 * 4 + quad;
      sx8 af[4];
#pragma unroll
      for (int i = 0; i < 4; ++i) {
        int row = i * 16 + ml;
        af[i] = *(const sx8*)&Ash[b][(row * 8 + (kq ^ (row & 7))) * 8];
      }
#pragma unroll
      for (int i = 0; i < 4; ++i)
#pragma unroll
        for (int j = 0; j < 2; ++j)
          acc[i][j] = __builtin_amdgcn_mfma_f32_16x16x32_bf16(af[i], bf[s2][j], acc[i][j], 0, 0, 0);
    }
  };
  auto sync_step = [&]() {
    __builtin_amdgcn_sched_barrier(0);
    asm volatile("s_waitcnt lgkmcnt(0)" ::: "memory");
    __builtin_amdgcn_s_barrier();
    __builtin_amdgcn_sched_barrier(0);
  };

  loadA(0, avA);
  loadA(1, avB);
  writeA(avA, 0);
  sync_step();

  for (int it = 0; it < 8; ++it) {
    int kt0 = it * 2;
    sx8 bf[2][2];
    loadB(kt0, bf);
    loadA(kt0 + 2 < 16 ? kt0 + 2 : 15, avA);
    compute(0, bf);
    writeA(avB, 1);
    sync_step();

    loadB(kt0 + 1, bf);
    loadA(kt0 + 3 < 16 ? kt0 + 3 : 15, avB);
    compute(1, bf);
    writeA(avA, 0);
    sync_step();
  }

  int grow = m_blk * 64;
  int gcol = n_blk * 128 + w * 32;
#pragma unroll
  for (int i = 0; i < 4; ++i) {
#pragma unroll
    for (int r = 0; r < 4; ++r) {
      int mrow = grow + i * 16 + quad * 4 + r;
      float p = 0.f;
#pragma unroll
      for (int j = 0; j < 2; ++j) {
        emb[(size_t)mrow * ED + gcol + j * 16 + ml] = f2bf(acc[i][j][r]);
        p += acc[i][j][r] * acc[i][j][r];
      }
#pragma unroll
      for (int off = 1; off < 16; off <<= 1) p += __shfl_xor(p, off, 16);
      if (ml == 0) atomicAdd(&rowssq[mrow], p);
    }
  }
}

// ---------------------------------------------------------------------------
// K2 (merged, replaces proto_partial + proto_reduce): per-class sums of
// (emb_s/||s||), LDS-accumulated, flushed via GLOBAL fp32 atomicAdd into
// Pacc[NC][ED]. Grid (32 chunks x 8 dim-slices) = 256 blocks, 256 rows each.
// Kills one kernel launch + 8MB Ppart write + 8MB read. 1M flush atomics,
// disjoint 16KB region per ds-slice. Pacc zeroed by k_prep.
// ---------------------------------------------------------------------------
__global__ __launch_bounds__(256) void k_proto(
    const unsigned short* __restrict__ embS, const float* __restrict__ rowssq,
    const int* __restrict__ labels, float* __restrict__ Pacc) {
  __shared__ float Pl[NC * 64];  // 16 KB: [class][dim-within-slice]
  int t = threadIdx.x;
#pragma unroll
  for (int i = 0; i < 16; ++i) Pl[i * 256 + t] = 0.f;
  __syncthreads();

  int w = t >> 6, lane = t & 63;
  int ds = blockIdx.y;            // dim slice: dims [ds*64, ds*64+64)
  int row0 = blockIdx.x * 256;    // 32 chunks of 256 rows
#pragma unroll 4
  for (int r = w; r < 256; r += 4) {
    int row = row0 + r;
    int lbl = labels[row];
    float scale = 1.0f / fmaxf(sqrtf(rowssq[row]), 1e-12f);
    float v = bf2f(embS[(size_t)row * ED + ds * 64 + lane]) * scale;
    atomicAdd(&Pl[lbl * 64 + lane], v);
  }
  __syncthreads();

#pragma unroll
  for (int i = 0; i < 16; ++i) {
    int idx = i * 256 + t;        // class = idx>>6, dim-in-slice = idx&63
    atomicAdd(&Pacc[(size_t)(idx >> 6) * ED + ds * 64 + (idx & 63)], Pl[idx]);
  }
}

// ---------------------------------------------------------------------------
// K3: class_scores = (emb_q @ P^T) / ||q|| + fused softmax.
// B-fragments now read from Pacc fp32 (L2-hot 128KB) with inline RNE cvt
// (matches the rounding k_proto_reduce used to apply).
// ---------------------------------------------------------------------------
__global__ __launch_bounds__(64) void k_scores(
    const unsigned short* __restrict__ embQ, const float* __restrict__ ssqQ,
    const float* __restrict__ Pacc, float* __restrict__ out) {
  int lane = threadIdx.x;
  int quad = lane >> 4, ml = lane & 15;
  int qrow0 = blockIdx.x * 16;

  fx4 acc[4];
#pragma unroll
  for (int i = 0; i < 4; ++i) acc[i] = fx4{0.f, 0.f, 0.f, 0.f};

#pragma unroll 4
  for (int ki = 0; ki < 16; ++ki) {
    sx8 a = *(const sx8*)&embQ[(size_t)(qrow0 + ml) * ED + ki * 32 + quad * 8];
    int d0 = ki * 32 + quad * 8;
#pragma unroll
    for (int nt = 0; nt < 4; ++nt) {
      const float* Prow = &Pacc[(size_t)(nt * 16 + ml) * ED + d0];
      fx4 p0 = *(const fx4*)Prow;
      fx4 p1 = *(const fx4*)(Prow + 4);
      ux8 bb;
      bb[0] = f2bf(p0.x); bb[1] = f2bf(p0.y); bb[2] = f2bf(p0.z); bb[3] = f2bf(p0.w);
      bb[4] = f2bf(p1.x); bb[5] = f2bf(p1.y); bb[6] = f2bf(p1.z); bb[7] = f2bf(p1.w);
      acc[nt] = __builtin_amdgcn_mfma_f32_16x16x32_bf16(a, *(sx8*)&bb, acc[nt], 0, 0, 0);
    }
  }

#pragma unroll
  for (int r = 0; r < 4; ++r) {
    int qq = qrow0 + quad * 4 + r;
    float scale = 1.0f / fmaxf(sqrtf(ssqQ[qq]), 1e-12f);
    float s[4];
#pragma unroll
    for (int nt = 0; nt < 4; ++nt) s[nt] = acc[nt][r] * scale;
    float m = fmaxf(fmaxf(s[0], s[1]), fmaxf(s[2], s[3]));
#pragma unroll
    for (int off = 1; off < 16; off <<= 1) m = fmaxf(m, __shfl_xor(m, off, 16));
    float e[4], ssum = 0.f;
#pragma unroll
    for (int nt = 0; nt < 4; ++nt) { e[nt] = __expf(s[nt] - m); ssum += e[nt]; }
#pragma unroll
    for (int off = 1; off < 16; off <<= 1) ssum += __shfl_xor(ssum, off, 16);
    float inv = 1.0f / ssum;
#pragma unroll
    for (int nt = 0; nt < 4; ++nt)
      out[(size_t)qq * NC + nt * 16 + ml] = e[nt] * inv;
  }
}

// ---------------------------------------------------------------------------
extern "C" void kernel_launch(void* const* d_in, const int* in_sizes, int n_in,
                              void* d_out, int out_size, void* d_ws, size_t ws_size,
                              hipStream_t stream) {
  const float* Xs     = (const float*)d_in[0];  // support_data [8192,1024]
  const int*   labels = (const int*)d_in[1];    // support_labels [8192]
  const float* Xq     = (const float*)d_in[2];  // query_data [8192,1024]
  const float* W      = (const float*)d_in[3];  // W [1024,512]
  float* out = (float*)d_out;

  char* ws = (char*)d_ws;
  size_t off = 0;
  unsigned short* Wtp = (unsigned short*)(ws + off); off += (size_t)ED * KDIM * 2;    // 1 MB (fragment-packed)
  unsigned short* emb = (unsigned short*)(ws + off); off += (size_t)NTOT * ED * 2;    // 16 MB
  float* rowssq = (float*)(ws + off); off += (size_t)NTOT * 4;                        // 64 KB
  float* Pacc   = (float*)(ws + off); off += (size_t)NC * ED * 4;                     // 128 KB

  k_prep<<<256, 256, 0, stream>>>(W, Wtp, rowssq, Pacc);
  k_gemm_embed<<<1024, 256, 0, stream>>>(Xs, Xq, Wtp, emb, rowssq);
  k_proto<<<dim3(32, 8), 256, 0, stream>>>(emb, rowssq, labels, Pacc);
  k_scores<<<NQ / 16, 64, 0, stream>>>(emb + (size_t)NS * ED, rowssq + NS, Pacc, out);
}